// Round 7
// baseline (144.220 us; speedup 1.0000x reference)
//
#include <hip/hip_runtime.h>

#pragma clang fp contract(off)

#define T_CAND 856
#define NW 14          // ceil(856/64)
#define NSH 16         // sub-histograms (split by (tid>>2)&15 to cut same-address atomics)
#define HSTR 513       // sub-hist stride in words (odd -> banks spread)

__device__ const int d_HW[5]  = {12800, 3200, 800, 208, 56};
__device__ const int d_K[5]   = {200, 200, 200, 200, 56};
__device__ const int d_OFF[5] = {0, 200, 400, 600, 800};

struct LevelPtrs {
  const float* loc[5];
  const float* cls[5];
  const float* reg[5];
  const int*   img;
};

__device__ __forceinline__ unsigned long long readlane64(unsigned long long v, int lane) {
  const unsigned lo = (unsigned)__builtin_amdgcn_readlane((int)(unsigned)(v & 0xFFFFFFFFULL), lane);
  const unsigned hi = (unsigned)__builtin_amdgcn_readlane((int)(unsigned)(v >> 32), lane);
  return ((unsigned long long)hi << 32) | lo;
}
__device__ __forceinline__ unsigned long long rfl64(unsigned long long v) {
  const unsigned lo = (unsigned)__builtin_amdgcn_readfirstlane((int)(unsigned)(v & 0xFFFFFFFFULL));
  const unsigned hi = (unsigned)__builtin_amdgcn_readfirstlane((int)(unsigned)(v >> 32));
  return ((unsigned long long)hi << 32) | lo;
}

// ---------------- Kernel 1: per (batch,level) stable top-K + decode ----------------
// Histogram radix-select; sigmoid cached in LDS; cutoff bucket found by a single-wave
// parallel suffix scan (was: serial 512-iter tid0 loop, ~5-8us of LDS latency chain).
__global__ __launch_bounds__(1024) void topk_kernel(LevelPtrs P,
    float* __restrict__ candPoly, float* __restrict__ candSc, unsigned* __restrict__ candValid,
    unsigned* __restrict__ pairCount) {
  __shared__ unsigned hist[NSH * HSTR];      // ~32.8 KB
  __shared__ unsigned histT[512];
  __shared__ __align__(16) unsigned long long gbuf[1024];  // 8 KB
  __shared__ float mcache[12800];            // 51.2 KB (max HW)
  __shared__ int gcount;
  __shared__ int cutB;
  const int blk = blockIdx.x;
  const int b = blk / 5, l = blk % 5;
  const int HW = d_HW[l], K = d_K[l], OFF = d_OFF[l];
  const float* cls = P.cls[l] + (size_t)b * HW;
  const float* reg = P.reg[l] + (size_t)b * 8 * HW;
  const float* loc = P.loc[l];
  const int tid = threadIdx.x;
  const int wave = tid >> 6, lane = tid & 63;

  if (blk == 0 && tid == 0) *pairCount = 0u;   // consumed next kernel (boundary-ordered)
  for (int t = tid; t < NSH * HSTR; t += 1024) hist[t] = 0u;
  if (tid == 0) gcount = 0;
  __syncthreads();

  // pass 1: sigmoid + cache + histogram of masked-score high bits (bucket = bits[31:21])
  const int sh = (tid >> 2) & (NSH - 1);
  for (int idx = tid; idx < HW; idx += 1024) {
    const float x = cls[idx];
    // correctly-rounded f32 sigmoid via double (bit-matched XLA in R1 — do not change)
    const float s = (float)(1.0 / (1.0 + exp(-(double)x)));
    const float m = (s > 0.05f) ? s : 0.0f;
    mcache[idx] = m;
    atomicAdd(&hist[sh * HSTR + (__float_as_uint(m) >> 21)], 1u);
  }
  __syncthreads();
  for (int t = tid; t < 512; t += 1024) {
    unsigned sum = 0;
#pragma unroll
    for (int h = 0; h < NSH; ++h) sum += hist[h * HSTR + t];
    histT[t] = sum;
  }
  __syncthreads();
  // single-wave suffix scan: cutB = largest t with sum_{u>=t} histT[u] >= K
  if (wave == 0) {
    const int t0 = lane * 8;
    int h[8], loc8[8];
#pragma unroll
    for (int k = 0; k < 8; ++k) h[k] = (int)histT[t0 + k];
    int run = 0;
#pragma unroll
    for (int k = 7; k >= 0; --k) { run += h[k]; loc8[k] = run; }
    int v = run;
#pragma unroll
    for (int d = 1; d < 64; d <<= 1) {
      const int u = __shfl_down(v, d);
      if (lane + d < 64) v += u;
    }
    const int excl = v - run;   // sum of totals of lanes > lane
    int cand = -1;
#pragma unroll
    for (int k = 7; k >= 0; --k)
      if (cand < 0 && excl + loc8[k] >= K) cand = t0 + k;
    const unsigned long long bal = __ballot(cand >= 0);
    const int hi = 63 - __builtin_clzll(bal);   // nonzero: total == HW >= K
    const int cb = __shfl(cand, hi);
    if (lane == 0) cutB = cb;
  }
  __syncthreads();

  // pass 2: gather all elements in buckets >= cutB from cache (<= 1024, validated R2+)
  const int cb = cutB;
  for (int idx = tid; idx < HW; idx += 1024) {
    const unsigned kb = __float_as_uint(mcache[idx]);
    if ((int)(kb >> 21) >= cb) {
      const int pos = atomicAdd(&gcount, 1);
      if (pos < 1024)
        gbuf[pos] = ((unsigned long long)kb << 32)
                  | (unsigned long long)(0xFFFFFFFFu - (unsigned)idx); // tie -> lower idx first
    }
  }
  __syncthreads();
  const int G = min(gcount, 1024);
  if (tid < 4 && G + tid < 1024) gbuf[G + tid] = 0ULL;   // pad so vector loop reads zeros
  __syncthreads();

  // rank-by-count + decode (vectorized LDS reads; pad keys 0 never count: any real key > 0)
  if (tid < G) {
    const unsigned long long my = gbuf[tid];
    const int G4 = (G + 3) & ~3;
    int rank = 0;
    const ulonglong2* g2 = (const ulonglong2*)gbuf;
    for (int j = 0; j < G4 / 2; j += 2) {
      const ulonglong2 a = g2[j], c = g2[j + 1];
      rank += (a.x > my) ? 1 : 0;
      rank += (a.y > my) ? 1 : 0;
      rank += (c.x > my) ? 1 : 0;
      rank += (c.y > my) ? 1 : 0;
    }
    if (rank < K) {
      const float val = __uint_as_float((unsigned)(my >> 32));
      const int idx = (int)(0xFFFFFFFFu - (unsigned)(my & 0xFFFFFFFFULL));
      const float hh = (float)P.img[b * 2 + 0];
      const float ww = (float)P.img[b * 2 + 1];
      const float xmax = ww - 1.0f, ymax = hh - 1.0f;
      const float lx = loc[idx * 2 + 0], ly = loc[idx * 2 + 1];
      const int go = b * T_CAND + OFF + rank;
#pragma unroll
      for (int q = 0; q < 4; ++q) {
        const float rx = reg[(2 * q + 0) * HW + idx];
        const float ry = reg[(2 * q + 1) * HW + idx];
        const float pxv = fminf(fmaxf(lx - rx, 0.0f), xmax);
        const float pyv = fminf(fmaxf(ly - ry, 0.0f), ymax);
        candPoly[go * 8 + 2 * q + 0] = pxv;
        candPoly[go * 8 + 2 * q + 1] = pyv;
      }
      const bool v = (val > 0.05f);   // bw/bh >= MIN_SIZE(0) always true after clip
      candSc[go]    = v ? sqrtf(val) : 0.0f;
      candValid[go] = v ? 1u : 0u;
    }
  }
}

// ---------------- Kernel 2: fused stable sort + AABB prescreen + MT zero -----------
// Per-batch block (2x1024). Phase A: rank-by-count sort (validated R2+), AABBs and
// valid flags kept in LDS. Phase B: zero MT. Phase C: 105 triangular 64x64 tiles,
// one per wave iteration; AABB-overlap (exact reject, validated R3+) pairs compacted
// to the global pair list.
__global__ __launch_bounds__(1024) void sort_aabb_kernel(
    const float* __restrict__ candPoly, const float* __restrict__ candSc,
    const unsigned* __restrict__ candValid,
    float* __restrict__ sPoly, float* __restrict__ sSc, unsigned* __restrict__ sValid,
    unsigned long long* __restrict__ MT, unsigned* __restrict__ pairList,
    unsigned* __restrict__ pairCount) {
  __shared__ __align__(16) unsigned long long key[T_CAND];
  __shared__ __align__(16) float4 aabbL[T_CAND];     // 13.7 KB
  __shared__ unsigned char validL[NW * 64];          // 896
  __shared__ unsigned long long vbits[NW];
  const int b = blockIdx.x, tid = threadIdx.x;
  const int wave = tid >> 6, lane = tid & 63;

  float sc = 0.0f;
  if (tid < T_CAND) {
    sc = candSc[b * T_CAND + tid];
    key[tid] = ((unsigned long long)__float_as_uint(sc) << 32)
             | (unsigned long long)(0xFFFFFFFFu - (unsigned)tid);
  }
  if (tid >= T_CAND && tid < NW * 64) validL[tid] = 0;
  __syncthreads();
  if (tid < T_CAND) {
    const unsigned long long my = key[tid];
    int rank = 0;
    const ulonglong2* k2 = (const ulonglong2*)key;
    for (int j = 0; j < T_CAND / 2; j += 2) {
      const ulonglong2 a = k2[j], c = k2[j + 1];
      rank += (a.x > my) ? 1 : 0;
      rank += (a.y > my) ? 1 : 0;
      rank += (c.x > my) ? 1 : 0;
      rank += (c.y > my) ? 1 : 0;
    }
    const unsigned vfl = candValid[b * T_CAND + tid];
    sSc[b * T_CAND + rank]    = sc;
    sValid[b * T_CAND + rank] = vfl;
    validL[rank] = (unsigned char)vfl;
    const float4* src = (const float4*)(candPoly + (size_t)(b * T_CAND + tid) * 8);
    const float4 s0 = src[0], s1 = src[1];
    float4* dst = (float4*)(sPoly + (size_t)(b * T_CAND + rank) * 8);
    dst[0] = s0;
    dst[1] = s1;
    float4 bb;  // minx,miny,maxx,maxy
    bb.x = fminf(fminf(s0.x, s0.z), fminf(s1.x, s1.z));
    bb.y = fminf(fminf(s0.y, s0.w), fminf(s1.y, s1.w));
    bb.z = fmaxf(fmaxf(s0.x, s0.z), fmaxf(s1.x, s1.z));
    bb.w = fmaxf(fmaxf(s0.y, s0.w), fmaxf(s1.y, s1.w));
    aabbL[rank] = bb;
  }
  __syncthreads();
  // zero this batch's MT (clip atomicOr's hit bits on top)
  {
    ulonglong2* m2 = (ulonglong2*)(MT + (size_t)b * NW * T_CAND);
    const ulonglong2 z = {0ULL, 0ULL};
    for (int t = tid; t < NW * T_CAND / 2; t += 1024) m2[t] = z;
  }
  if (wave < NW) {
    const unsigned long long ball = __ballot(validL[wave * 64 + lane] != 0);
    if (lane == 0) vbits[wave] = ball;
  }
  __syncthreads();

  // triangular tiles (it,jt), jt>=it: 105 tiles over 16 waves
  for (int t = wave; t < (NW * (NW + 1)) / 2; t += 16) {
    int it = 0, rem = t;
    while (rem >= NW - it) { rem -= NW - it; ++it; }
    const int jt = it + rem;
    const int j = jt * 64 + lane;
    const bool jv = ((vbits[jt] >> lane) & 1ULL) != 0ULL;
    const float4 jb = aabbL[j < T_CAND ? j : (T_CAND - 1)];
    unsigned long long roww = 0ULL;
    const unsigned long long ivb = vbits[it];
    for (int q = 0; q < 64; ++q) {
      const int irow = it * 64 + q;
      const float4 ib = aabbL[irow < T_CAND ? irow : (T_CAND - 1)];  // LDS broadcast
      const bool iv = ((ivb >> q) & 1ULL) != 0ULL;
      const bool ov = !(ib.z < jb.x || jb.z < ib.x || ib.w < jb.y || jb.w < ib.y);
      const bool pred = iv && jv && (j > irow) && ov;
      const unsigned long long w = __ballot(pred);
      if (lane == q) roww = w;
    }
    // compact: lane L owns row (it*64+L)'s candidate word
    const int cnt = __popcll(roww);
    int incl = cnt;
#pragma unroll
    for (int d = 1; d < 64; d <<= 1) {
      const int v = __shfl_up(incl, d);
      if (lane >= d) incl += v;
    }
    const int ex = incl - cnt;
    int base = 0;
    if (lane == 63 && incl > 0) base = (int)atomicAdd(pairCount, (unsigned)incl);
    base = __shfl(base, 63);
    unsigned off = (unsigned)(base + ex);
    unsigned long long tb = roww;
    const int iRow = it * 64 + lane;
    while (tb) {
      const int jb2 = (int)__builtin_ctzll(tb);
      tb &= tb - 1;
      pairList[off++] = ((unsigned)b << 20) | ((unsigned)iRow << 10) | (unsigned)(jt * 64 + jb2);
    }
  }
}

// ---------------- Kernel 3: polygon-clip IoU on surviving pairs --------------------
__global__ __launch_bounds__(256) void clip_kernel(
    const unsigned* __restrict__ pairList, const unsigned* __restrict__ pairCount,
    const float* __restrict__ sPoly, unsigned long long* __restrict__ MT) {
  __shared__ float VX[2][8][256];
  __shared__ float VY[2][8][256];
  const int tid = threadIdx.x;
  const unsigned count = *pairCount;
  for (unsigned t0 = blockIdx.x * 256 + tid; t0 < count; t0 += gridDim.x * 256) {
    const unsigned pk = pairList[t0];
    const int b = (pk >> 20) & 1, i = (pk >> 10) & 1023, j = pk & 1023;
    const float4* Ap4 = (const float4*)(sPoly + (size_t)(b * T_CAND + i) * 8);
    const float4 a01 = Ap4[0], a23 = Ap4[1];
    const float ax0 = a01.x, ay0 = a01.y, ax1 = a01.z, ay1 = a01.w,
                ax2 = a23.x, ay2 = a23.y, ax3 = a23.z, ay3 = a23.w;
    const float4* Bp4 = (const float4*)(sPoly + (size_t)(b * T_CAND + j) * 8);
    const float4 b01 = Bp4[0], b23 = Bp4[1];
    const float bx0 = b01.x, by0 = b01.y, bx1 = b01.z, by1 = b01.w,
                bx2 = b23.x, by2 = b23.y, bx3 = b23.z, by3 = b23.w;
    // signed 2*area of B (same term order as reference) -> orientation
    float sB = bx0 * by1 - bx1 * by0;
    sB += bx1 * by2 - bx2 * by1;
    sB += bx2 * by3 - bx3 * by2;
    sB += bx3 * by0 - bx0 * by3;
    const float orient = (sB >= 0.0f) ? 1.0f : -1.0f;

    VX[0][0][tid] = ax0; VY[0][0][tid] = ay0;
    VX[0][1][tid] = ax1; VY[0][1][tid] = ay1;
    VX[0][2][tid] = ax2; VY[0][2][tid] = ay2;
    VX[0][3][tid] = ax3; VY[0][3][tid] = ay3;
    int n = 4;
    const float bex[5] = {bx0, bx1, bx2, bx3, bx0};
    const float bey[5] = {by0, by1, by2, by3, by0};
#pragma unroll
    for (int e = 0; e < 4; ++e) {
      const int src = e & 1, dst = src ^ 1;
      const float p1x = bex[e], p1y = bey[e];
      const float dx = bex[e + 1] - p1x, dy = bey[e + 1] - p1y;
      int cnt = 0;
      int pidx = n - 1;                       // JAX gather clamps (incl. -1 -> 0)
      pidx = pidx < 0 ? 0 : (pidx > 7 ? 7 : pidx);
      float px = VX[src][pidx][tid], py = VY[src][pidx][tid];
      float sp = orient * (dx * (py - p1y) - dy * (px - p1x));
      for (int k = 0; k < 8; ++k) {
        if (k >= n) break;                    // k>=n iterations are provable no-ops
        const float cx = VX[src][k][tid], cy = VY[src][k][tid];
        const float sc2 = orient * (dx * (cy - p1y) - dy * (cx - p1x));
        const bool cin = (sc2 >= 0.0f), pin = (sp >= 0.0f);
        const float denom = sp - sc2;
        const float dd = (fabsf(denom) > 1e-9f) ? denom : 1e-9f;
        const float t = sp / dd;
        const float ipx = px + t * (cx - px);
        const float ipy = py + t * (cy - py);
        const bool e1 = (cin != pin);
        if (e1 && cnt < 8) { VX[dst][cnt][tid] = ipx; VY[dst][cnt][tid] = ipy; }
        cnt += e1 ? 1 : 0;                    // cnt may pass 8: writes dropped (mode='drop')
        if (cin && cnt < 8) { VX[dst][cnt][tid] = cx; VY[dst][cnt][tid] = cy; }
        cnt += cin ? 1 : 0;
        px = cx; py = cy; sp = sc2;           // prev == V[k-1]; identical value reuse
      }
      n = cnt;
    }
    // shoelace on final buffer (buf 0 after 4 ping-pongs)
    float a = 0.0f;
    for (int k = 0; k < 8; ++k) {
      if (k >= n) break;
      const int nxt = (k == n - 1) ? 0 : ((k + 1 > 7) ? 7 : (k + 1));  // clamp like JAX
      const float xk = VX[0][k][tid], yk = VY[0][k][tid];
      const float xn = VX[0][nxt][tid], yn = VY[0][nxt][tid];
      a += xk * yn - xn * yk;
    }
    const float inter = 0.5f * fabsf(a);
    float aA = ax0 * ay1 - ax1 * ay0;
    aA += ax1 * ay2 - ax2 * ay1;
    aA += ax2 * ay3 - ax3 * ay2;
    aA += ax3 * ay0 - ax0 * ay3;
    const float areaA = 0.5f * fabsf(aA);
    const float areaB = 0.5f * fabsf(sB);
    const float uni = areaA + areaB - inter;
    const float iou = inter / fmaxf(uni, 1e-9f);
    if (iou > 0.5f)
      atomicOr(&MT[((size_t)b * NW + (j >> 6)) * T_CAND + i], 1ULL << (j & 63));
  }
}

// ---------------- Kernel 4: greedy NMS resolve (scalarized) + top-100 emit ---------
__global__ __launch_bounds__(1024) void nms_resolve_emit_kernel(
    const unsigned long long* __restrict__ MT, const unsigned* __restrict__ sValid,
    const float* __restrict__ sPoly, const float* __restrict__ sSc, float* __restrict__ out) {
  __shared__ __align__(16) unsigned long long mt[NW * T_CAND];  // 95,872 B
  __shared__ unsigned long long vb[16];
  __shared__ unsigned long long kw[NW];
  const int b = blockIdx.x;
  const int tid = threadIdx.x;
  const int wave = tid >> 6, lane = tid & 63;

  {
    const ulonglong2* g2 = (const ulonglong2*)(MT + (size_t)b * NW * T_CAND);
    ulonglong2* l2 = (ulonglong2*)mt;
    for (int t = tid; t < NW * T_CAND / 2; t += 1024) l2[t] = g2[t];
  }
  if (wave < NW) {
    const int idx = wave * 64 + lane;
    const bool v = (idx < T_CAND) && (sValid[b * T_CAND + idx] != 0u);
    const unsigned long long ball = __ballot(v);
    if (lane == 0) vb[wave] = ball;
  }
  __syncthreads();

  if (wave == 0) {
    unsigned long long kwreg = 0ULL;   // lane q holds keep-word of resolved block q
    for (int q = 0; q < NW; ++q) {
      const unsigned long long* col = &mt[q * T_CAND];
      const int nrow = q * 64 + lane;
      const unsigned long long sup = col[nrow < T_CAND ? nrow : (T_CAND - 1)];
      unsigned long long acc = 0ULL;
      for (int wp = 0; wp < q; ++wp) {
        const unsigned long long row = col[wp * 64 + lane];
        const unsigned long long kword = readlane64(kwreg, wp);
        acc |= ((kword >> lane) & 1ULL) ? row : 0ULL;
      }
#pragma unroll
      for (int m = 1; m < 64; m <<= 1)
        acc |= (unsigned long long)__shfl_xor((long long)acc, m, 64);
      const unsigned long long S = rfl64(acc);
      const unsigned long long validq = rfl64(vb[q]);
      unsigned long long alive = validq & ~S;
      const unsigned long long suppr = __ballot(sup != 0ULL);
      unsigned long long rem = alive & suppr;
      while (rem) {
        const int s = (int)__builtin_ctzll(rem);
        rem &= rem - 1;
        if ((alive >> s) & 1ULL) {
          alive &= ~readlane64(sup, s);
          rem &= alive;
        }
      }
      if (lane == q) kwreg = alive;
    }
    if (lane < NW) kw[lane] = kwreg;
  }
  __syncthreads();

  if (tid < 100) {
    const int o = tid;
    int totalKeep = 0;
    for (int w = 0; w < NW; ++w) totalKeep += __popcll(kw[w]);
    const bool kept = o < totalKeep;
    int idx = 0;
    if (kept) {
      int r = o, w = 0;
      unsigned long long word = 0ULL;
      for (; w < NW; ++w) {
        word = kw[w];
        const int c = __popcll(word);
        if (r < c) break;
        r -= c;
      }
      for (int p = 0; p < r; ++p) word &= word - 1;
      idx = w * 64 + (__ffsll(word) - 1);
    } else {
      int r = o - totalKeep, w = 0;
      unsigned long long word = 0ULL;
      for (; w < NW; ++w) {
        const unsigned long long mk = (w == NW - 1) ? ((1ULL << (T_CAND - 64 * (NW - 1))) - 1ULL)
                                                    : ~0ULL;
        word = (~kw[w]) & mk;
        const int c = __popcll(word);
        if (r < c) break;
        r -= c;
      }
      for (int p = 0; p < r; ++p) word &= word - 1;
      idx = w * 64 + (__ffsll(word) - 1);
    }
    const float4* pp = (const float4*)(sPoly + (size_t)(b * T_CAND + idx) * 8);
    float4* ob2 = (float4*)(out + (size_t)b * 800 + (size_t)o * 8);
    ob2[0] = pp[0];
    ob2[1] = pp[1];
    out[1600 + b * 100 + o] = kept ? sSc[b * T_CAND + idx] : 0.0f;  // where(ok, top_s, 0)
    out[1800 + b * 100 + o] = 1.0f;                                 // labels always 1 (C=1)
    out[2000 + b * 100 + o] = kept ? 1.0f : 0.0f;                   // ok
  }
}

extern "C" void kernel_launch(void* const* d_in, const int* in_sizes, int n_in,
                              void* d_out, int out_size, void* d_ws, size_t ws_size,
                              hipStream_t stream) {
  (void)n_in; (void)out_size; (void)ws_size;
  LevelPtrs P;
  const bool interleaved = (in_sizes[2] == 204800);
  for (int l = 0; l < 5; ++l) {
    if (interleaved) {
      P.loc[l] = (const float*)d_in[4 * l + 0];
      P.cls[l] = (const float*)d_in[4 * l + 1];
      P.reg[l] = (const float*)d_in[4 * l + 2];
    } else {
      P.loc[l] = (const float*)d_in[l];
      P.cls[l] = (const float*)d_in[5 + l];
      P.reg[l] = (const float*)d_in[10 + l];
    }
  }
  P.img = (const int*)d_in[20];

  char* ws = (char*)d_ws;
  float*    candPoly  = (float*)(ws + 0);          // 54784
  float*    candSc    = (float*)(ws + 54784);      // 6848
  unsigned* candValid = (unsigned*)(ws + 61632);   // 6848
  float*    sPoly     = (float*)(ws + 68480);      // 54784 (16B aligned)
  float*    sSc       = (float*)(ws + 123264);     // 6848
  unsigned* sValid    = (unsigned*)(ws + 130112);  // 6848
  unsigned long long* MT = (unsigned long long*)(ws + 136960); // 191744 -> ends 328704
  unsigned* pairCount = (unsigned*)(ws + 328704);  // 4 (padded to 328720)
  unsigned* pairList  = (unsigned*)(ws + 328720);  // max 856*855/2*2*4 = 2,927,520 B

  topk_kernel<<<dim3(10), dim3(1024), 0, stream>>>(P, candPoly, candSc, candValid, pairCount);
  sort_aabb_kernel<<<dim3(2), dim3(1024), 0, stream>>>(candPoly, candSc, candValid,
                                                       sPoly, sSc, sValid, MT,
                                                       pairList, pairCount);
  clip_kernel<<<dim3(512), dim3(256), 0, stream>>>(pairList, pairCount, sPoly, MT);
  nms_resolve_emit_kernel<<<dim3(2), dim3(1024), 0, stream>>>(MT, sValid, sPoly, sSc,
                                                              (float*)d_out);
}

// Round 8
// 91.814 us; speedup vs baseline: 1.5708x; 1.5708x over previous
//
#include <hip/hip_runtime.h>

#pragma clang fp contract(off)

#define T_CAND 856
#define NW 14          // ceil(856/64)
#define NSH 16         // sub-histograms (split by (tid>>2)&15 to cut same-address atomics)
#define HSTR 513       // sub-hist stride in words (odd -> banks spread)

__device__ const int d_HW[5]  = {12800, 3200, 800, 208, 56};
__device__ const int d_K[5]   = {200, 200, 200, 200, 56};
__device__ const int d_OFF[5] = {0, 200, 400, 600, 800};

struct LevelPtrs {
  const float* loc[5];
  const float* cls[5];
  const float* reg[5];
  const int*   img;
};

__device__ __forceinline__ unsigned long long readlane64(unsigned long long v, int lane) {
  const unsigned lo = (unsigned)__builtin_amdgcn_readlane((int)(unsigned)(v & 0xFFFFFFFFULL), lane);
  const unsigned hi = (unsigned)__builtin_amdgcn_readlane((int)(unsigned)(v >> 32), lane);
  return ((unsigned long long)hi << 32) | lo;
}
__device__ __forceinline__ unsigned long long rfl64(unsigned long long v) {
  const unsigned lo = (unsigned)__builtin_amdgcn_readfirstlane((int)(unsigned)(v & 0xFFFFFFFFULL));
  const unsigned hi = (unsigned)__builtin_amdgcn_readfirstlane((int)(unsigned)(v >> 32));
  return ((unsigned long long)hi << 32) | lo;
}

// ---------------- Kernel 1: per (batch,level) stable top-K + decode ----------------
// Histogram radix-select; sigmoid cached in LDS; cutoff bucket found by a single-wave
// parallel suffix scan. Rank-by-count of unique keys == stable sort (validated R1+).
__global__ __launch_bounds__(1024) void topk_kernel(LevelPtrs P,
    float* __restrict__ candPoly, float* __restrict__ candSc, unsigned* __restrict__ candValid) {
  __shared__ unsigned hist[NSH * HSTR];      // ~32.8 KB
  __shared__ unsigned histT[512];
  __shared__ __align__(16) unsigned long long gbuf[1024];  // 8 KB
  __shared__ float mcache[12800];            // 51.2 KB (max HW)
  __shared__ int gcount;
  __shared__ int cutB;
  const int blk = blockIdx.x;
  const int b = blk / 5, l = blk % 5;
  const int HW = d_HW[l], K = d_K[l], OFF = d_OFF[l];
  const float* cls = P.cls[l] + (size_t)b * HW;
  const float* reg = P.reg[l] + (size_t)b * 8 * HW;
  const float* loc = P.loc[l];
  const int tid = threadIdx.x;
  const int wave = tid >> 6, lane = tid & 63;

  for (int t = tid; t < NSH * HSTR; t += 1024) hist[t] = 0u;
  if (tid == 0) gcount = 0;
  __syncthreads();

  // pass 1: sigmoid + cache + histogram of masked-score high bits (bucket = bits[31:21])
  const int sh = (tid >> 2) & (NSH - 1);
  for (int idx = tid; idx < HW; idx += 1024) {
    const float x = cls[idx];
    // correctly-rounded f32 sigmoid via double (bit-matched XLA in R1 — do not change)
    const float s = (float)(1.0 / (1.0 + exp(-(double)x)));
    const float m = (s > 0.05f) ? s : 0.0f;
    mcache[idx] = m;
    atomicAdd(&hist[sh * HSTR + (__float_as_uint(m) >> 21)], 1u);
  }
  __syncthreads();
  for (int t = tid; t < 512; t += 1024) {
    unsigned sum = 0;
#pragma unroll
    for (int h = 0; h < NSH; ++h) sum += hist[h * HSTR + t];
    histT[t] = sum;
  }
  __syncthreads();
  // single-wave suffix scan: cutB = largest t with sum_{u>=t} histT[u] >= K (validated R7)
  if (wave == 0) {
    const int t0 = lane * 8;
    int h[8], loc8[8];
#pragma unroll
    for (int k = 0; k < 8; ++k) h[k] = (int)histT[t0 + k];
    int run = 0;
#pragma unroll
    for (int k = 7; k >= 0; --k) { run += h[k]; loc8[k] = run; }
    int v = run;
#pragma unroll
    for (int d = 1; d < 64; d <<= 1) {
      const int u = __shfl_down(v, d);
      if (lane + d < 64) v += u;
    }
    const int excl = v - run;   // sum of totals of lanes > lane
    int cand = -1;
#pragma unroll
    for (int k = 7; k >= 0; --k)
      if (cand < 0 && excl + loc8[k] >= K) cand = t0 + k;
    const unsigned long long bal = __ballot(cand >= 0);
    const int hi = 63 - __builtin_clzll(bal);   // nonzero: total == HW >= K
    const int cb = __shfl(cand, hi);
    if (lane == 0) cutB = cb;
  }
  __syncthreads();

  // pass 2: gather all elements in buckets >= cutB from cache (<= 1024, validated R2+)
  const int cb = cutB;
  for (int idx = tid; idx < HW; idx += 1024) {
    const unsigned kb = __float_as_uint(mcache[idx]);
    if ((int)(kb >> 21) >= cb) {
      const int pos = atomicAdd(&gcount, 1);
      if (pos < 1024)
        gbuf[pos] = ((unsigned long long)kb << 32)
                  | (unsigned long long)(0xFFFFFFFFu - (unsigned)idx); // tie -> lower idx first
    }
  }
  __syncthreads();
  const int G = min(gcount, 1024);
  if (tid < 4 && G + tid < 1024) gbuf[G + tid] = 0ULL;   // pad so vector loop reads zeros
  __syncthreads();

  // rank-by-count + decode (vectorized LDS reads; pad keys 0 never count: any real key > 0)
  if (tid < G) {
    const unsigned long long my = gbuf[tid];
    const int G4 = (G + 3) & ~3;
    int rank = 0;
    const ulonglong2* g2 = (const ulonglong2*)gbuf;
    for (int j = 0; j < G4 / 2; j += 2) {
      const ulonglong2 a = g2[j], c = g2[j + 1];
      rank += (a.x > my) ? 1 : 0;
      rank += (a.y > my) ? 1 : 0;
      rank += (c.x > my) ? 1 : 0;
      rank += (c.y > my) ? 1 : 0;
    }
    if (rank < K) {
      const float val = __uint_as_float((unsigned)(my >> 32));
      const int idx = (int)(0xFFFFFFFFu - (unsigned)(my & 0xFFFFFFFFULL));
      const float hh = (float)P.img[b * 2 + 0];
      const float ww = (float)P.img[b * 2 + 1];
      const float xmax = ww - 1.0f, ymax = hh - 1.0f;
      const float lx = loc[idx * 2 + 0], ly = loc[idx * 2 + 1];
      const int go = b * T_CAND + OFF + rank;
#pragma unroll
      for (int q = 0; q < 4; ++q) {
        const float rx = reg[(2 * q + 0) * HW + idx];
        const float ry = reg[(2 * q + 1) * HW + idx];
        const float pxv = fminf(fmaxf(lx - rx, 0.0f), xmax);
        const float pyv = fminf(fmaxf(ly - ry, 0.0f), ymax);
        candPoly[go * 8 + 2 * q + 0] = pxv;
        candPoly[go * 8 + 2 * q + 1] = pyv;
      }
      const bool v = (val > 0.05f);   // bw/bh >= MIN_SIZE(0) always true after clip
      candSc[go]    = v ? sqrtf(val) : 0.0f;
      candValid[go] = v ? 1u : 0u;
    }
  }
}

// ---------------- Kernel 2: per-batch stable sort + AABB emit (R6-validated) -------
__global__ __launch_bounds__(1024) void sort_kernel(
    const float* __restrict__ candPoly, const float* __restrict__ candSc,
    const unsigned* __restrict__ candValid,
    float* __restrict__ sPoly, float* __restrict__ sSc, unsigned* __restrict__ sValid,
    float* __restrict__ sAABB) {
  __shared__ __align__(16) unsigned long long key[T_CAND];
  const int b = blockIdx.x, tid = threadIdx.x;
  float sc = 0.0f;
  if (tid < T_CAND) {
    sc = candSc[b * T_CAND + tid];
    key[tid] = ((unsigned long long)__float_as_uint(sc) << 32)
             | (unsigned long long)(0xFFFFFFFFu - (unsigned)tid);
  }
  __syncthreads();
  if (tid < T_CAND) {
    const unsigned long long my = key[tid];
    int rank = 0;
    const ulonglong2* k2 = (const ulonglong2*)key;
    for (int j = 0; j < T_CAND / 2; j += 2) {
      const ulonglong2 a = k2[j], c = k2[j + 1];
      rank += (a.x > my) ? 1 : 0;
      rank += (a.y > my) ? 1 : 0;
      rank += (c.x > my) ? 1 : 0;
      rank += (c.y > my) ? 1 : 0;
    }
    sSc[b * T_CAND + rank]    = sc;
    sValid[b * T_CAND + rank] = candValid[b * T_CAND + tid];
    const float4* src = (const float4*)(candPoly + (size_t)(b * T_CAND + tid) * 8);
    const float4 s0 = src[0], s1 = src[1];
    float4* dst = (float4*)(sPoly + (size_t)(b * T_CAND + rank) * 8);
    dst[0] = s0;
    dst[1] = s1;
    float4 bb;  // minx,miny,maxx,maxy
    bb.x = fminf(fminf(s0.x, s0.z), fminf(s1.x, s1.z));
    bb.y = fminf(fminf(s0.y, s0.w), fminf(s1.y, s1.w));
    bb.z = fmaxf(fmaxf(s0.x, s0.z), fmaxf(s1.x, s1.z));
    bb.w = fmaxf(fmaxf(s0.y, s0.w), fmaxf(s1.y, s1.w));
    *(float4*)(sAABB + (size_t)(b * T_CAND + rank) * 4) = bb;
  }
}

// ---------------- Kernel 3: fused AABB-prescreen + polygon-clip per 64x64 tile -----
// Grid (105 triangular tiles, 2 batches) x 256 threads. Block (it,jt) EXCLUSIVELY owns
// MT word jt for rows it*64..it*64+63 and stores complete words (no atomics to global,
// no pre-zeroing). Resolve reads only diagonal (sup) and above-diagonal (wp<q) words,
// all of which are covered by the triangular grid. AABB reject = exact (validated R3+);
// clip math bit-identical (validated R1+).
__global__ __launch_bounds__(256) void tile_clip_kernel(
    const float* __restrict__ sPoly, const unsigned* __restrict__ sValid,
    const float* __restrict__ sAABB, unsigned long long* __restrict__ MT) {
  __shared__ float VX[2][8][256];
  __shared__ float VY[2][8][256];
  __shared__ __align__(16) float4 ra[64];
  __shared__ unsigned rv[64];
  __shared__ unsigned long long cw[64];
  __shared__ unsigned long long ow[64];
  __shared__ unsigned pl[4096];
  __shared__ int cnt;
  const int b = blockIdx.y;
  int it = 0, rem = blockIdx.x;
  while (rem >= NW - it) { rem -= NW - it; ++it; }
  const int jt = it + rem;
  const int tid = threadIdx.x;
  const int wave = tid >> 6, lane = tid & 63;

  if (tid == 0) cnt = 0;
  if (tid < 64) {
    const int row = it * 64 + tid;
    const int rc = row < T_CAND ? row : (T_CAND - 1);
    ra[tid] = *(const float4*)(sAABB + (size_t)(b * T_CAND + rc) * 4);
    rv[tid] = (row < T_CAND) ? sValid[b * T_CAND + row] : 0u;
    ow[tid] = 0ULL;
  }
  __syncthreads();

  // prescreen: 4 waves x 16 rows each; lane = column offset
  const int j = jt * 64 + lane;
  const int jcl = j < T_CAND ? j : (T_CAND - 1);
  const float4 jb = *(const float4*)(sAABB + (size_t)(b * T_CAND + jcl) * 4);
  const bool jv = (j < T_CAND) && (sValid[b * T_CAND + jcl] != 0u);
#pragma unroll
  for (int k = 0; k < 16; ++k) {
    const int r = wave * 16 + k;
    const int irow = it * 64 + r;
    const float4 ib = ra[r];                       // uniform LDS broadcast
    const bool iv = rv[r] != 0u;
    const bool ov = !(ib.z < jb.x || jb.z < ib.x || ib.w < jb.y || jb.w < ib.y);
    const bool pred = iv && jv && (j > irow) && ov;
    const unsigned long long w = __ballot(pred);
    if (lane == 0) cw[r] = w;
  }
  __syncthreads();
  // emit pair list (threads 0..63 each own one row)
  if (tid < 64) {
    unsigned long long w = cw[tid];
    const int c = __popcll(w);
    int off = c ? atomicAdd(&cnt, c) : 0;
    while (w) {
      const int jo = (int)__builtin_ctzll(w);
      w &= w - 1;
      pl[off++] = ((unsigned)tid << 6) | (unsigned)jo;
    }
  }
  __syncthreads();
  const int total = cnt;
  for (int p = tid; p < total; p += 256) {
    const unsigned pk = pl[p];
    const int io = (int)(pk >> 6), jo = (int)(pk & 63u);
    const int i = it * 64 + io, jj = jt * 64 + jo;
    const float4* Ap4 = (const float4*)(sPoly + (size_t)(b * T_CAND + i) * 8);
    const float4 a01 = Ap4[0], a23 = Ap4[1];
    const float ax0 = a01.x, ay0 = a01.y, ax1 = a01.z, ay1 = a01.w,
                ax2 = a23.x, ay2 = a23.y, ax3 = a23.z, ay3 = a23.w;
    const float4* Bp4 = (const float4*)(sPoly + (size_t)(b * T_CAND + jj) * 8);
    const float4 b01 = Bp4[0], b23 = Bp4[1];
    const float bx0 = b01.x, by0 = b01.y, bx1 = b01.z, by1 = b01.w,
                bx2 = b23.x, by2 = b23.y, bx3 = b23.z, by3 = b23.w;
    // signed 2*area of B (same term order as reference) -> orientation
    float sB = bx0 * by1 - bx1 * by0;
    sB += bx1 * by2 - bx2 * by1;
    sB += bx2 * by3 - bx3 * by2;
    sB += bx3 * by0 - bx0 * by3;
    const float orient = (sB >= 0.0f) ? 1.0f : -1.0f;

    VX[0][0][tid] = ax0; VY[0][0][tid] = ay0;
    VX[0][1][tid] = ax1; VY[0][1][tid] = ay1;
    VX[0][2][tid] = ax2; VY[0][2][tid] = ay2;
    VX[0][3][tid] = ax3; VY[0][3][tid] = ay3;
    int n = 4;
    const float bex[5] = {bx0, bx1, bx2, bx3, bx0};
    const float bey[5] = {by0, by1, by2, by3, by0};
#pragma unroll
    for (int e = 0; e < 4; ++e) {
      const int src = e & 1, dst = src ^ 1;
      const float p1x = bex[e], p1y = bey[e];
      const float dx = bex[e + 1] - p1x, dy = bey[e + 1] - p1y;
      int cn = 0;
      int pidx = n - 1;                       // JAX gather clamps (incl. -1 -> 0)
      pidx = pidx < 0 ? 0 : (pidx > 7 ? 7 : pidx);
      float px = VX[src][pidx][tid], py = VY[src][pidx][tid];
      float sp = orient * (dx * (py - p1y) - dy * (px - p1x));
      for (int k = 0; k < 8; ++k) {
        if (k >= n) break;                    // k>=n iterations are provable no-ops
        const float cx = VX[src][k][tid], cy = VY[src][k][tid];
        const float sc2 = orient * (dx * (cy - p1y) - dy * (cx - p1x));
        const bool cin = (sc2 >= 0.0f), pin = (sp >= 0.0f);
        const float denom = sp - sc2;
        const float dd = (fabsf(denom) > 1e-9f) ? denom : 1e-9f;
        const float t = sp / dd;
        const float ipx = px + t * (cx - px);
        const float ipy = py + t * (cy - py);
        const bool e1 = (cin != pin);
        if (e1 && cn < 8) { VX[dst][cn][tid] = ipx; VY[dst][cn][tid] = ipy; }
        cn += e1 ? 1 : 0;                     // cn may pass 8: writes dropped (mode='drop')
        if (cin && cn < 8) { VX[dst][cn][tid] = cx; VY[dst][cn][tid] = cy; }
        cn += cin ? 1 : 0;
        px = cx; py = cy; sp = sc2;           // prev == V[k-1]; identical value reuse
      }
      n = cn;
    }
    // shoelace on final buffer (buf 0 after 4 ping-pongs)
    float a = 0.0f;
    for (int k = 0; k < 8; ++k) {
      if (k >= n) break;
      const int nxt = (k == n - 1) ? 0 : ((k + 1 > 7) ? 7 : (k + 1));  // clamp like JAX
      const float xk = VX[0][k][tid], yk = VY[0][k][tid];
      const float xn = VX[0][nxt][tid], yn = VY[0][nxt][tid];
      a += xk * yn - xn * yk;
    }
    const float inter = 0.5f * fabsf(a);
    float aA = ax0 * ay1 - ax1 * ay0;
    aA += ax1 * ay2 - ax2 * ay1;
    aA += ax2 * ay3 - ax3 * ay2;
    aA += ax3 * ay0 - ax0 * ay3;
    const float areaA = 0.5f * fabsf(aA);
    const float areaB = 0.5f * fabsf(sB);
    const float uni = areaA + areaB - inter;
    const float iou = inter / fmaxf(uni, 1e-9f);
    if (iou > 0.5f) atomicOr(&ow[io], 1ULL << jo);
  }
  __syncthreads();
  if (tid < 64) {
    const int row = it * 64 + tid;
    if (row < T_CAND) MT[((size_t)b * NW + jt) * T_CAND + row] = ow[tid];
  }
}

// ---------------- Kernel 4: greedy NMS resolve (scalarized) + top-100 emit ---------
__global__ __launch_bounds__(1024) void nms_resolve_emit_kernel(
    const unsigned long long* __restrict__ MT, const unsigned* __restrict__ sValid,
    const float* __restrict__ sPoly, const float* __restrict__ sSc, float* __restrict__ out) {
  __shared__ __align__(16) unsigned long long mt[NW * T_CAND];  // 95,872 B
  __shared__ unsigned long long vb[16];
  __shared__ unsigned long long kw[NW];
  const int b = blockIdx.x;
  const int tid = threadIdx.x;
  const int wave = tid >> 6, lane = tid & 63;

  {
    const ulonglong2* g2 = (const ulonglong2*)(MT + (size_t)b * NW * T_CAND);
    ulonglong2* l2 = (ulonglong2*)mt;
    for (int t = tid; t < NW * T_CAND / 2; t += 1024) l2[t] = g2[t];
  }
  if (wave < NW) {
    const int idx = wave * 64 + lane;
    const bool v = (idx < T_CAND) && (sValid[b * T_CAND + idx] != 0u);
    const unsigned long long ball = __ballot(v);
    if (lane == 0) vb[wave] = ball;
  }
  __syncthreads();

  if (wave == 0) {
    unsigned long long kwreg = 0ULL;   // lane q holds keep-word of resolved block q
    for (int q = 0; q < NW; ++q) {
      const unsigned long long* col = &mt[q * T_CAND];
      const int nrow = q * 64 + lane;
      const unsigned long long sup = col[nrow < T_CAND ? nrow : (T_CAND - 1)];
      unsigned long long acc = 0ULL;
      for (int wp = 0; wp < q; ++wp) {
        const unsigned long long row = col[wp * 64 + lane];
        const unsigned long long kword = readlane64(kwreg, wp);
        acc |= ((kword >> lane) & 1ULL) ? row : 0ULL;
      }
#pragma unroll
      for (int m = 1; m < 64; m <<= 1)
        acc |= (unsigned long long)__shfl_xor((long long)acc, m, 64);
      const unsigned long long S = rfl64(acc);
      const unsigned long long validq = rfl64(vb[q]);
      unsigned long long alive = validq & ~S;
      const unsigned long long suppr = __ballot(sup != 0ULL);
      unsigned long long rem = alive & suppr;
      while (rem) {
        const int s = (int)__builtin_ctzll(rem);
        rem &= rem - 1;
        if ((alive >> s) & 1ULL) {
          alive &= ~readlane64(sup, s);
          rem &= alive;
        }
      }
      if (lane == q) kwreg = alive;
    }
    if (lane < NW) kw[lane] = kwreg;
  }
  __syncthreads();

  if (tid < 100) {
    const int o = tid;
    int totalKeep = 0;
    for (int w = 0; w < NW; ++w) totalKeep += __popcll(kw[w]);
    const bool kept = o < totalKeep;
    int idx = 0;
    if (kept) {
      int r = o, w = 0;
      unsigned long long word = 0ULL;
      for (; w < NW; ++w) {
        word = kw[w];
        const int c = __popcll(word);
        if (r < c) break;
        r -= c;
      }
      for (int p = 0; p < r; ++p) word &= word - 1;
      idx = w * 64 + (__ffsll(word) - 1);
    } else {
      int r = o - totalKeep, w = 0;
      unsigned long long word = 0ULL;
      for (; w < NW; ++w) {
        const unsigned long long mk = (w == NW - 1) ? ((1ULL << (T_CAND - 64 * (NW - 1))) - 1ULL)
                                                    : ~0ULL;
        word = (~kw[w]) & mk;
        const int c = __popcll(word);
        if (r < c) break;
        r -= c;
      }
      for (int p = 0; p < r; ++p) word &= word - 1;
      idx = w * 64 + (__ffsll(word) - 1);
    }
    const float4* pp = (const float4*)(sPoly + (size_t)(b * T_CAND + idx) * 8);
    float4* ob2 = (float4*)(out + (size_t)b * 800 + (size_t)o * 8);
    ob2[0] = pp[0];
    ob2[1] = pp[1];
    out[1600 + b * 100 + o] = kept ? sSc[b * T_CAND + idx] : 0.0f;  // where(ok, top_s, 0)
    out[1800 + b * 100 + o] = 1.0f;                                 // labels always 1 (C=1)
    out[2000 + b * 100 + o] = kept ? 1.0f : 0.0f;                   // ok
  }
}

extern "C" void kernel_launch(void* const* d_in, const int* in_sizes, int n_in,
                              void* d_out, int out_size, void* d_ws, size_t ws_size,
                              hipStream_t stream) {
  (void)n_in; (void)out_size; (void)ws_size;
  LevelPtrs P;
  const bool interleaved = (in_sizes[2] == 204800);
  for (int l = 0; l < 5; ++l) {
    if (interleaved) {
      P.loc[l] = (const float*)d_in[4 * l + 0];
      P.cls[l] = (const float*)d_in[4 * l + 1];
      P.reg[l] = (const float*)d_in[4 * l + 2];
    } else {
      P.loc[l] = (const float*)d_in[l];
      P.cls[l] = (const float*)d_in[5 + l];
      P.reg[l] = (const float*)d_in[10 + l];
    }
  }
  P.img = (const int*)d_in[20];

  char* ws = (char*)d_ws;
  float*    candPoly  = (float*)(ws + 0);          // 54784
  float*    candSc    = (float*)(ws + 54784);      // 6848
  unsigned* candValid = (unsigned*)(ws + 61632);   // 6848
  float*    sPoly     = (float*)(ws + 68480);      // 54784 (16B aligned)
  float*    sSc       = (float*)(ws + 123264);     // 6848
  unsigned* sValid    = (unsigned*)(ws + 130112);  // 6848
  unsigned long long* MT = (unsigned long long*)(ws + 136960); // 191744 -> ends 328704
  float*    sAABB     = (float*)(ws + 328704);     // 2*856*4*4 = 27392

  topk_kernel<<<dim3(10), dim3(1024), 0, stream>>>(P, candPoly, candSc, candValid);
  sort_kernel<<<dim3(2), dim3(1024), 0, stream>>>(candPoly, candSc, candValid,
                                                  sPoly, sSc, sValid, sAABB);
  tile_clip_kernel<<<dim3((NW * (NW + 1)) / 2, 2), dim3(256), 0, stream>>>(sPoly, sValid,
                                                                           sAABB, MT);
  nms_resolve_emit_kernel<<<dim3(2), dim3(1024), 0, stream>>>(MT, sValid, sPoly, sSc,
                                                              (float*)d_out);
}

// Round 9
// 74.754 us; speedup vs baseline: 1.9293x; 1.2282x over previous
//
#include <hip/hip_runtime.h>

#pragma clang fp contract(off)

#define T_CAND 856
#define NW 14          // ceil(856/64)
#define NSH 16         // sub-histograms (split by (tid>>2)&15 to cut same-address atomics)
#define HSTR 513       // sub-hist stride in words (odd -> banks spread)

__device__ const int d_HW[5]  = {12800, 3200, 800, 208, 56};
__device__ const int d_K[5]   = {200, 200, 200, 200, 56};
__device__ const int d_OFF[5] = {0, 200, 400, 600, 800};

struct LevelPtrs {
  const float* loc[5];
  const float* cls[5];
  const float* reg[5];
  const int*   img;
};

__device__ __forceinline__ unsigned long long readlane64(unsigned long long v, int lane) {
  const unsigned lo = (unsigned)__builtin_amdgcn_readlane((int)(unsigned)(v & 0xFFFFFFFFULL), lane);
  const unsigned hi = (unsigned)__builtin_amdgcn_readlane((int)(unsigned)(v >> 32), lane);
  return ((unsigned long long)hi << 32) | lo;
}
__device__ __forceinline__ unsigned long long rfl64(unsigned long long v) {
  const unsigned lo = (unsigned)__builtin_amdgcn_readfirstlane((int)(unsigned)(v & 0xFFFFFFFFULL));
  const unsigned hi = (unsigned)__builtin_amdgcn_readfirstlane((int)(unsigned)(v >> 32));
  return ((unsigned long long)hi << 32) | lo;
}

// ---------------- Kernel 1: per (batch,level) stable top-K + decode ----------------
__global__ __launch_bounds__(1024) void topk_kernel(LevelPtrs P,
    float* __restrict__ candPoly, float* __restrict__ candSc, unsigned* __restrict__ candValid,
    unsigned* __restrict__ pairCount) {
  __shared__ unsigned hist[NSH * HSTR];      // ~32.8 KB
  __shared__ unsigned histT[512];
  __shared__ __align__(16) unsigned long long gbuf[1024];  // 8 KB
  __shared__ float mcache[12800];            // 51.2 KB (max HW)
  __shared__ int gcount;
  __shared__ int cutB;
  const int blk = blockIdx.x;
  const int b = blk / 5, l = blk % 5;
  const int HW = d_HW[l], K = d_K[l], OFF = d_OFF[l];
  const float* cls = P.cls[l] + (size_t)b * HW;
  const float* reg = P.reg[l] + (size_t)b * 8 * HW;
  const float* loc = P.loc[l];
  const int tid = threadIdx.x;
  const int wave = tid >> 6, lane = tid & 63;

  if (blk == 0 && tid == 0) *pairCount = 0u;   // consumed 2 kernels later (boundary-ordered)
  for (int t = tid; t < NSH * HSTR; t += 1024) hist[t] = 0u;
  if (tid == 0) gcount = 0;
  __syncthreads();

  // pass 1: sigmoid + cache + histogram of masked-score high bits (bucket = bits[31:21])
  const int sh = (tid >> 2) & (NSH - 1);
  for (int idx = tid; idx < HW; idx += 1024) {
    const float x = cls[idx];
    // correctly-rounded f32 sigmoid via double (bit-matched XLA in R1 — do not change)
    const float s = (float)(1.0 / (1.0 + exp(-(double)x)));
    const float m = (s > 0.05f) ? s : 0.0f;
    mcache[idx] = m;
    atomicAdd(&hist[sh * HSTR + (__float_as_uint(m) >> 21)], 1u);
  }
  __syncthreads();
  for (int t = tid; t < 512; t += 1024) {
    unsigned sum = 0;
#pragma unroll
    for (int h = 0; h < NSH; ++h) sum += hist[h * HSTR + t];
    histT[t] = sum;
  }
  __syncthreads();
  // single-wave suffix scan: cutB = largest t with sum_{u>=t} histT[u] >= K (validated R7)
  if (wave == 0) {
    const int t0 = lane * 8;
    int h[8], loc8[8];
#pragma unroll
    for (int k = 0; k < 8; ++k) h[k] = (int)histT[t0 + k];
    int run = 0;
#pragma unroll
    for (int k = 7; k >= 0; --k) { run += h[k]; loc8[k] = run; }
    int v = run;
#pragma unroll
    for (int d = 1; d < 64; d <<= 1) {
      const int u = __shfl_down(v, d);
      if (lane + d < 64) v += u;
    }
    const int excl = v - run;   // sum of totals of lanes > lane
    int cand = -1;
#pragma unroll
    for (int k = 7; k >= 0; --k)
      if (cand < 0 && excl + loc8[k] >= K) cand = t0 + k;
    const unsigned long long bal = __ballot(cand >= 0);
    const int hi = 63 - __builtin_clzll(bal);   // nonzero: total == HW >= K
    const int cb = __shfl(cand, hi);
    if (lane == 0) cutB = cb;
  }
  __syncthreads();

  // pass 2: gather all elements in buckets >= cutB from cache (<= 1024, validated R2+)
  const int cb = cutB;
  for (int idx = tid; idx < HW; idx += 1024) {
    const unsigned kb = __float_as_uint(mcache[idx]);
    if ((int)(kb >> 21) >= cb) {
      const int pos = atomicAdd(&gcount, 1);
      if (pos < 1024)
        gbuf[pos] = ((unsigned long long)kb << 32)
                  | (unsigned long long)(0xFFFFFFFFu - (unsigned)idx); // tie -> lower idx first
    }
  }
  __syncthreads();
  const int G = min(gcount, 1024);
  if (tid < 4 && G + tid < 1024) gbuf[G + tid] = 0ULL;   // pad so vector loop reads zeros
  __syncthreads();

  // rank-by-count + decode (vectorized LDS reads; pad keys 0 never count: any real key > 0)
  if (tid < G) {
    const unsigned long long my = gbuf[tid];
    const int G4 = (G + 3) & ~3;
    int rank = 0;
    const ulonglong2* g2 = (const ulonglong2*)gbuf;
    for (int j = 0; j < G4 / 2; j += 2) {
      const ulonglong2 a = g2[j], c = g2[j + 1];
      rank += (a.x > my) ? 1 : 0;
      rank += (a.y > my) ? 1 : 0;
      rank += (c.x > my) ? 1 : 0;
      rank += (c.y > my) ? 1 : 0;
    }
    if (rank < K) {
      const float val = __uint_as_float((unsigned)(my >> 32));
      const int idx = (int)(0xFFFFFFFFu - (unsigned)(my & 0xFFFFFFFFULL));
      const float hh = (float)P.img[b * 2 + 0];
      const float ww = (float)P.img[b * 2 + 1];
      const float xmax = ww - 1.0f, ymax = hh - 1.0f;
      const float lx = loc[idx * 2 + 0], ly = loc[idx * 2 + 1];
      const int go = b * T_CAND + OFF + rank;
#pragma unroll
      for (int q = 0; q < 4; ++q) {
        const float rx = reg[(2 * q + 0) * HW + idx];
        const float ry = reg[(2 * q + 1) * HW + idx];
        const float pxv = fminf(fmaxf(lx - rx, 0.0f), xmax);
        const float pyv = fminf(fmaxf(ly - ry, 0.0f), ymax);
        candPoly[go * 8 + 2 * q + 0] = pxv;
        candPoly[go * 8 + 2 * q + 1] = pyv;
      }
      const bool v = (val > 0.05f);   // bw/bh >= MIN_SIZE(0) always true after clip
      candSc[go]    = v ? sqrtf(val) : 0.0f;
      candValid[go] = v ? 1u : 0u;
    }
  }
}

// ---------------- Kernel 2: per-batch stable sort + AABB emit (R6-validated) -------
__global__ __launch_bounds__(1024) void sort_kernel(
    const float* __restrict__ candPoly, const float* __restrict__ candSc,
    const unsigned* __restrict__ candValid,
    float* __restrict__ sPoly, float* __restrict__ sSc, unsigned* __restrict__ sValid,
    float* __restrict__ sAABB) {
  __shared__ __align__(16) unsigned long long key[T_CAND];
  const int b = blockIdx.x, tid = threadIdx.x;
  float sc = 0.0f;
  if (tid < T_CAND) {
    sc = candSc[b * T_CAND + tid];
    key[tid] = ((unsigned long long)__float_as_uint(sc) << 32)
             | (unsigned long long)(0xFFFFFFFFu - (unsigned)tid);
  }
  __syncthreads();
  if (tid < T_CAND) {
    const unsigned long long my = key[tid];
    int rank = 0;
    const ulonglong2* k2 = (const ulonglong2*)key;
    for (int j = 0; j < T_CAND / 2; j += 2) {
      const ulonglong2 a = k2[j], c = k2[j + 1];
      rank += (a.x > my) ? 1 : 0;
      rank += (a.y > my) ? 1 : 0;
      rank += (c.x > my) ? 1 : 0;
      rank += (c.y > my) ? 1 : 0;
    }
    sSc[b * T_CAND + rank]    = sc;
    sValid[b * T_CAND + rank] = candValid[b * T_CAND + tid];
    const float4* src = (const float4*)(candPoly + (size_t)(b * T_CAND + tid) * 8);
    const float4 s0 = src[0], s1 = src[1];
    float4* dst = (float4*)(sPoly + (size_t)(b * T_CAND + rank) * 8);
    dst[0] = s0;
    dst[1] = s1;
    float4 bb;  // minx,miny,maxx,maxy
    bb.x = fminf(fminf(s0.x, s0.z), fminf(s1.x, s1.z));
    bb.y = fminf(fminf(s0.y, s0.w), fminf(s1.y, s1.w));
    bb.z = fmaxf(fmaxf(s0.x, s0.z), fmaxf(s1.x, s1.z));
    bb.w = fmaxf(fmaxf(s0.y, s0.w), fmaxf(s1.y, s1.w));
    *(float4*)(sAABB + (size_t)(b * T_CAND + rank) * 4) = bb;
  }
}

// ---------------- Kernel 3: AABB prescreen per tile -> global pair list + MT zero --
// Grid (105 triangular tiles, 2 batches) x 256. Predicate validated R8. One global
// atomicAdd per tile. Tile (it,jt) zero-stores its owned MT words (resolve reads only
// triangular words -> full coverage, validated R8). clip_kernel atomicOrs on top.
__global__ __launch_bounds__(256) void pairs_kernel(
    const unsigned* __restrict__ sValid, const float* __restrict__ sAABB,
    unsigned long long* __restrict__ MT, unsigned* __restrict__ pairList,
    unsigned* __restrict__ pairCount) {
  __shared__ __align__(16) float4 ra[64];
  __shared__ unsigned rv[64];
  __shared__ unsigned long long cw[64];
  __shared__ int rowoff[64];
  __shared__ int lcnt;
  __shared__ int gbase;
  const int b = blockIdx.y;
  int it = 0, rem = blockIdx.x;
  while (rem >= NW - it) { rem -= NW - it; ++it; }
  const int jt = it + rem;
  const int tid = threadIdx.x;
  const int wave = tid >> 6, lane = tid & 63;

  if (tid == 0) lcnt = 0;
  if (tid < 64) {
    const int row = it * 64 + tid;
    const int rc = row < T_CAND ? row : (T_CAND - 1);
    ra[tid] = *(const float4*)(sAABB + (size_t)(b * T_CAND + rc) * 4);
    rv[tid] = (row < T_CAND) ? sValid[b * T_CAND + row] : 0u;
    if (row < T_CAND) MT[((size_t)b * NW + jt) * T_CAND + row] = 0ULL;
  }
  __syncthreads();

  // prescreen: 4 waves x 16 rows; lane = column offset
  const int j = jt * 64 + lane;
  const int jcl = j < T_CAND ? j : (T_CAND - 1);
  const float4 jb = *(const float4*)(sAABB + (size_t)(b * T_CAND + jcl) * 4);
  const bool jv = (j < T_CAND) && (sValid[b * T_CAND + jcl] != 0u);
#pragma unroll
  for (int k = 0; k < 16; ++k) {
    const int r = wave * 16 + k;
    const int irow = it * 64 + r;
    const float4 ib = ra[r];                       // uniform LDS broadcast
    const bool iv = rv[r] != 0u;
    const bool ov = !(ib.z < jb.x || jb.z < ib.x || ib.w < jb.y || jb.w < ib.y);
    const bool pred = iv && jv && (j > irow) && ov;
    const unsigned long long w = __ballot(pred);
    if (lane == 0) cw[r] = w;
  }
  __syncthreads();
  if (tid < 64) {
    const int c = __popcll(cw[tid]);
    rowoff[tid] = c ? atomicAdd(&lcnt, c) : 0;
  }
  __syncthreads();
  if (tid == 0) gbase = lcnt ? (int)atomicAdd(pairCount, (unsigned)lcnt) : 0;
  __syncthreads();
  if (tid < 64) {
    unsigned long long w = cw[tid];
    unsigned off = (unsigned)(gbase + rowoff[tid]);
    const int iRow = it * 64 + tid;
    while (w) {
      const int jo = (int)__builtin_ctzll(w);
      w &= w - 1;
      pairList[off++] = ((unsigned)b << 20) | ((unsigned)iRow << 10) | (unsigned)(jt * 64 + jo);
    }
  }
}

// ---------------- Kernel 4: register-only polygon-clip IoU over the pair list ------
// Polygon kept entirely in named VGPRs (no LDS aliasing stalls): reads are static
// (full unroll), writes at runtime cnt become 8-way selects, prev tracked as the last
// push landing in slot<=7 (== validated V[clamp(n-1,0,7)], incl. cnt>8 bowtie case),
// shoelace nxt is a 2-way select. Arithmetic order bit-identical to validated clip.
__global__ __launch_bounds__(256) void clip_kernel(
    const unsigned* __restrict__ pairList, const unsigned* __restrict__ pairCount,
    const float* __restrict__ sPoly, unsigned long long* __restrict__ MT) {
  const int tid = threadIdx.x;
  const unsigned count = *pairCount;
  for (unsigned t0 = blockIdx.x * 256 + tid; t0 < count; t0 += gridDim.x * 256) {
    const unsigned pk = pairList[t0];
    const int b = (pk >> 20) & 1, i = (pk >> 10) & 1023, j = pk & 1023;
    const float4* Ap4 = (const float4*)(sPoly + (size_t)(b * T_CAND + i) * 8);
    const float4 a01 = Ap4[0], a23 = Ap4[1];
    const float ax0 = a01.x, ay0 = a01.y, ax1 = a01.z, ay1 = a01.w,
                ax2 = a23.x, ay2 = a23.y, ax3 = a23.z, ay3 = a23.w;
    const float4* Bp4 = (const float4*)(sPoly + (size_t)(b * T_CAND + j) * 8);
    const float4 b01 = Bp4[0], b23 = Bp4[1];
    const float bx0 = b01.x, by0 = b01.y, bx1 = b01.z, by1 = b01.w,
                bx2 = b23.x, by2 = b23.y, bx3 = b23.z, by3 = b23.w;
    // signed 2*area of B (same term order as reference) -> orientation
    float sB = bx0 * by1 - bx1 * by0;
    sB += bx1 * by2 - bx2 * by1;
    sB += bx2 * by3 - bx3 * by2;
    sB += bx3 * by0 - bx0 * by3;
    const float orient = (sB >= 0.0f) ? 1.0f : -1.0f;
    // 2*area of A (before clip clobbers nothing; A regs stay live anyway)
    float aA = ax0 * ay1 - ax1 * ay0;
    aA += ax1 * ay2 - ax2 * ay1;
    aA += ax2 * ay3 - ax3 * ay2;
    aA += ax3 * ay0 - ax0 * ay3;

    float s0x = ax0, s0y = ay0, s1x = ax1, s1y = ay1,
          s2x = ax2, s2y = ay2, s3x = ax3, s3y = ay3,
          s4x = 0.f, s4y = 0.f, s5x = 0.f, s5y = 0.f,
          s6x = 0.f, s6y = 0.f, s7x = 0.f, s7y = 0.f;
    int n = 4;
    float lastx = ax3, lasty = ay3;          // V[n-1] of initial polygon
    const float bex[5] = {bx0, bx1, bx2, bx3, bx0};
    const float bey[5] = {by0, by1, by2, by3, by0};

#define PUSH(w_, vx_, vy_)                                              \
    {                                                                   \
      const bool w__ = (w_);                                            \
      const float vx__ = (vx_), vy__ = (vy_);                           \
      t0x = (w__ && cnt == 0) ? vx__ : t0x; t0y = (w__ && cnt == 0) ? vy__ : t0y; \
      t1x = (w__ && cnt == 1) ? vx__ : t1x; t1y = (w__ && cnt == 1) ? vy__ : t1y; \
      t2x = (w__ && cnt == 2) ? vx__ : t2x; t2y = (w__ && cnt == 2) ? vy__ : t2y; \
      t3x = (w__ && cnt == 3) ? vx__ : t3x; t3y = (w__ && cnt == 3) ? vy__ : t3y; \
      t4x = (w__ && cnt == 4) ? vx__ : t4x; t4y = (w__ && cnt == 4) ? vy__ : t4y; \
      t5x = (w__ && cnt == 5) ? vx__ : t5x; t5y = (w__ && cnt == 5) ? vy__ : t5y; \
      t6x = (w__ && cnt == 6) ? vx__ : t6x; t6y = (w__ && cnt == 6) ? vy__ : t6y; \
      t7x = (w__ && cnt == 7) ? vx__ : t7x; t7y = (w__ && cnt == 7) ? vy__ : t7y; \
      nlx = (w__ && cnt < 8) ? vx__ : nlx;  nly = (w__ && cnt < 8) ? vy__ : nly;  \
      cnt += w__ ? 1 : 0;                                               \
    }

#define CLIP_K(k_, sx_, sy_)                                            \
    {                                                                   \
      const bool act = (k_) < n;                                        \
      const float cx = sx_, cy = sy_;                                   \
      const float sc2 = orient * (dx * (cy - p1y) - dy * (cx - p1x));   \
      const bool cin = (sc2 >= 0.0f), pin = (sp >= 0.0f);               \
      const float den = sp - sc2;                                       \
      const float dd = (fabsf(den) > 1e-9f) ? den : 1e-9f;              \
      const float tt = sp / dd;                                         \
      const float ipx = px + tt * (cx - px);                            \
      const float ipy = py + tt * (cy - py);                            \
      PUSH(act && (cin != pin), ipx, ipy);                              \
      PUSH(act && cin, cx, cy);                                         \
      px = cx; py = cy; sp = sc2;                                       \
    }

#pragma unroll
    for (int e = 0; e < 4; ++e) {
      const float p1x = bex[e], p1y = bey[e];
      const float dx = bex[e + 1] - p1x, dy = bey[e + 1] - p1y;
      float t0x = 0.f, t0y = 0.f, t1x = 0.f, t1y = 0.f, t2x = 0.f, t2y = 0.f,
            t3x = 0.f, t3y = 0.f, t4x = 0.f, t4y = 0.f, t5x = 0.f, t5y = 0.f,
            t6x = 0.f, t6y = 0.f, t7x = 0.f, t7y = 0.f;
      float nlx = lastx, nly = lasty;
      int cnt = 0;
      float px = lastx, py = lasty;
      float sp = orient * (dx * (py - p1y) - dy * (px - p1x));
      CLIP_K(0, s0x, s0y) CLIP_K(1, s1x, s1y) CLIP_K(2, s2x, s2y) CLIP_K(3, s3x, s3y)
      CLIP_K(4, s4x, s4y) CLIP_K(5, s5x, s5y) CLIP_K(6, s6x, s6y) CLIP_K(7, s7x, s7y)
      s0x = t0x; s0y = t0y; s1x = t1x; s1y = t1y; s2x = t2x; s2y = t2y;
      s3x = t3x; s3y = t3y; s4x = t4x; s4y = t4y; s5x = t5x; s5y = t5y;
      s6x = t6x; s6y = t6y; s7x = t7x; s7y = t7y;
      lastx = nlx; lasty = nly;
      n = cnt;           // raw (may exceed 8) — matches validated semantics
    }
#undef CLIP_K
#undef PUSH

    // shoelace: term_k = (k==n-1) ? xk*y0 - x0*yk : xk*y_{k+1} - x_{k+1}*yk, if k<n.
    // (for k=7 the non-wrap nxt clamps to 7 -> term 0, matching validated clamp.)
    float a = 0.0f;
#define SHOE(k_, xk_, yk_, xn_, yn_)                                    \
    {                                                                   \
      const bool act = (k_) < n;                                        \
      const bool wrap = (k_) == n - 1;                                  \
      const float xn = wrap ? s0x : (xn_);                              \
      const float yn = wrap ? s0y : (yn_);                              \
      const float term = (xk_) * yn - xn * (yk_);                       \
      a += act ? term : 0.0f;                                           \
    }
    SHOE(0, s0x, s0y, s1x, s1y) SHOE(1, s1x, s1y, s2x, s2y)
    SHOE(2, s2x, s2y, s3x, s3y) SHOE(3, s3x, s3y, s4x, s4y)
    SHOE(4, s4x, s4y, s5x, s5y) SHOE(5, s5x, s5y, s6x, s6y)
    SHOE(6, s6x, s6y, s7x, s7y) SHOE(7, s7x, s7y, s7x, s7y)
#undef SHOE
    const float inter = 0.5f * fabsf(a);
    const float areaA = 0.5f * fabsf(aA);
    const float areaB = 0.5f * fabsf(sB);
    const float uni = areaA + areaB - inter;
    const float iou = inter / fmaxf(uni, 1e-9f);
    if (iou > 0.5f)
      atomicOr(&MT[((size_t)b * NW + (j >> 6)) * T_CAND + i], 1ULL << (j & 63));
  }
}

// ---------------- Kernel 5: greedy NMS resolve (scalarized) + top-100 emit ---------
__global__ __launch_bounds__(1024) void nms_resolve_emit_kernel(
    const unsigned long long* __restrict__ MT, const unsigned* __restrict__ sValid,
    const float* __restrict__ sPoly, const float* __restrict__ sSc, float* __restrict__ out) {
  __shared__ __align__(16) unsigned long long mt[NW * T_CAND];  // 95,872 B
  __shared__ unsigned long long vb[16];
  __shared__ unsigned long long kw[NW];
  const int b = blockIdx.x;
  const int tid = threadIdx.x;
  const int wave = tid >> 6, lane = tid & 63;

  {
    const ulonglong2* g2 = (const ulonglong2*)(MT + (size_t)b * NW * T_CAND);
    ulonglong2* l2 = (ulonglong2*)mt;
    for (int t = tid; t < NW * T_CAND / 2; t += 1024) l2[t] = g2[t];
  }
  if (wave < NW) {
    const int idx = wave * 64 + lane;
    const bool v = (idx < T_CAND) && (sValid[b * T_CAND + idx] != 0u);
    const unsigned long long ball = __ballot(v);
    if (lane == 0) vb[wave] = ball;
  }
  __syncthreads();

  if (wave == 0) {
    unsigned long long kwreg = 0ULL;   // lane q holds keep-word of resolved block q
    for (int q = 0; q < NW; ++q) {
      const unsigned long long* col = &mt[q * T_CAND];
      const int nrow = q * 64 + lane;
      const unsigned long long sup = col[nrow < T_CAND ? nrow : (T_CAND - 1)];
      unsigned long long acc = 0ULL;
      for (int wp = 0; wp < q; ++wp) {
        const unsigned long long row = col[wp * 64 + lane];
        const unsigned long long kword = readlane64(kwreg, wp);
        acc |= ((kword >> lane) & 1ULL) ? row : 0ULL;
      }
#pragma unroll
      for (int m = 1; m < 64; m <<= 1)
        acc |= (unsigned long long)__shfl_xor((long long)acc, m, 64);
      const unsigned long long S = rfl64(acc);
      const unsigned long long validq = rfl64(vb[q]);
      unsigned long long alive = validq & ~S;
      const unsigned long long suppr = __ballot(sup != 0ULL);
      unsigned long long rem = alive & suppr;
      while (rem) {
        const int s = (int)__builtin_ctzll(rem);
        rem &= rem - 1;
        if ((alive >> s) & 1ULL) {
          alive &= ~readlane64(sup, s);
          rem &= alive;
        }
      }
      if (lane == q) kwreg = alive;
    }
    if (lane < NW) kw[lane] = kwreg;
  }
  __syncthreads();

  if (tid < 100) {
    const int o = tid;
    int totalKeep = 0;
    for (int w = 0; w < NW; ++w) totalKeep += __popcll(kw[w]);
    const bool kept = o < totalKeep;
    int idx = 0;
    if (kept) {
      int r = o, w = 0;
      unsigned long long word = 0ULL;
      for (; w < NW; ++w) {
        word = kw[w];
        const int c = __popcll(word);
        if (r < c) break;
        r -= c;
      }
      for (int p = 0; p < r; ++p) word &= word - 1;
      idx = w * 64 + (__ffsll(word) - 1);
    } else {
      int r = o - totalKeep, w = 0;
      unsigned long long word = 0ULL;
      for (; w < NW; ++w) {
        const unsigned long long mk = (w == NW - 1) ? ((1ULL << (T_CAND - 64 * (NW - 1))) - 1ULL)
                                                    : ~0ULL;
        word = (~kw[w]) & mk;
        const int c = __popcll(word);
        if (r < c) break;
        r -= c;
      }
      for (int p = 0; p < r; ++p) word &= word - 1;
      idx = w * 64 + (__ffsll(word) - 1);
    }
    const float4* pp = (const float4*)(sPoly + (size_t)(b * T_CAND + idx) * 8);
    float4* ob2 = (float4*)(out + (size_t)b * 800 + (size_t)o * 8);
    ob2[0] = pp[0];
    ob2[1] = pp[1];
    out[1600 + b * 100 + o] = kept ? sSc[b * T_CAND + idx] : 0.0f;  // where(ok, top_s, 0)
    out[1800 + b * 100 + o] = 1.0f;                                 // labels always 1 (C=1)
    out[2000 + b * 100 + o] = kept ? 1.0f : 0.0f;                   // ok
  }
}

extern "C" void kernel_launch(void* const* d_in, const int* in_sizes, int n_in,
                              void* d_out, int out_size, void* d_ws, size_t ws_size,
                              hipStream_t stream) {
  (void)n_in; (void)out_size; (void)ws_size;
  LevelPtrs P;
  const bool interleaved = (in_sizes[2] == 204800);
  for (int l = 0; l < 5; ++l) {
    if (interleaved) {
      P.loc[l] = (const float*)d_in[4 * l + 0];
      P.cls[l] = (const float*)d_in[4 * l + 1];
      P.reg[l] = (const float*)d_in[4 * l + 2];
    } else {
      P.loc[l] = (const float*)d_in[l];
      P.cls[l] = (const float*)d_in[5 + l];
      P.reg[l] = (const float*)d_in[10 + l];
    }
  }
  P.img = (const int*)d_in[20];

  char* ws = (char*)d_ws;
  float*    candPoly  = (float*)(ws + 0);          // 54784
  float*    candSc    = (float*)(ws + 54784);      // 6848
  unsigned* candValid = (unsigned*)(ws + 61632);   // 6848
  float*    sPoly     = (float*)(ws + 68480);      // 54784 (16B aligned)
  float*    sSc       = (float*)(ws + 123264);     // 6848
  unsigned* sValid    = (unsigned*)(ws + 130112);  // 6848
  unsigned long long* MT = (unsigned long long*)(ws + 136960); // 191744 -> ends 328704
  float*    sAABB     = (float*)(ws + 328704);     // 27392 -> 356096
  unsigned* pairCount = (unsigned*)(ws + 356096);  // 4 (pad to 356112)
  unsigned* pairList  = (unsigned*)(ws + 356112);  // max 856*855/2*2*4 = 2,927,520 B

  topk_kernel<<<dim3(10), dim3(1024), 0, stream>>>(P, candPoly, candSc, candValid, pairCount);
  sort_kernel<<<dim3(2), dim3(1024), 0, stream>>>(candPoly, candSc, candValid,
                                                  sPoly, sSc, sValid, sAABB);
  pairs_kernel<<<dim3((NW * (NW + 1)) / 2, 2), dim3(256), 0, stream>>>(sValid, sAABB, MT,
                                                                       pairList, pairCount);
  clip_kernel<<<dim3(512), dim3(256), 0, stream>>>(pairList, pairCount, sPoly, MT);
  nms_resolve_emit_kernel<<<dim3(2), dim3(1024), 0, stream>>>(MT, sValid, sPoly, sSc,
                                                              (float*)d_out);
}